// Round 3
// baseline (320.983 us; speedup 1.0000x reference)
//
#include <hip/hip_runtime.h>
#include <hip/hip_bf16.h>
#include <cstdint>

// CrossAttentionMultiHead: B=8, C=512, H=W=64 (S=4096), L=77, E=768, heads=4 (dh=128), GN groups=8.
// FP32 I/O (reference is jnp.float32); attention_mask int32. Compute in bf16 MFMA, fp32 accum.
// Pipeline: k_prep Wq->bf16 | per slice: k1 K/V proj | k0 x->xT (fp32->bf16 transpose) |
// k2 fused Qproj+attention (MFMA) + GN partials | k3 GroupNorm apply in-place on fp32 d_out.

typedef __attribute__((ext_vector_type(8))) short short8;
typedef __attribute__((ext_vector_type(4))) short short4v;
typedef __attribute__((ext_vector_type(4))) float f32x4;

#define DEV __device__ __forceinline__

DEV float bf2f(unsigned short u){ union{uint32_t i; float f;} x; x.i = ((uint32_t)u) << 16; return x.f; }
DEV unsigned short f2bf(float f){ __hip_bfloat16 h = __float2bfloat16(f); return *reinterpret_cast<unsigned short*>(&h); }
DEV short8 ld8(const unsigned short* p){ return *reinterpret_cast<const short8*>(p); }
DEV f32x4 ldf4(const float* p){ return *reinterpret_cast<const f32x4*>(p); }

// ---------------------------------------------------------------- k_prep: Wq fp32 -> bf16
__global__ __launch_bounds__(256) void k_prep(const float* __restrict__ Wq,
                                              unsigned short* __restrict__ wsWq){
  int i = (blockIdx.x * 256 + threadIdx.x) * 4;
  f32x4 v = ldf4(&Wq[i]);
  short4v o;
  #pragma unroll
  for (int j = 0; j < 4; ++j) o[j] = (short)f2bf(v[j]);
  *reinterpret_cast<short4v*>(&wsWq[i]) = o;
}

// ---------------------------------------------------------------- k0: x[b][c][s] fp32 -> xT[bz][s-s_base][c] bf16
__global__ __launch_bounds__(256) void k0_transpose(const float* __restrict__ x,
                                                    unsigned short* __restrict__ xT,
                                                    int b0, int s_base, int slen){
  __shared__ unsigned short t[64 * 72];          // 64x64 tile, stride 72, XOR-swizzled s-octets
  const int tid = threadIdx.x;
  const int s0 = s_base + blockIdx.x * 64, c0 = blockIdx.y * 64, bz = blockIdx.z;
  const int bg = b0 + bz;
  #pragma unroll
  for (int it = 0; it < 2; ++it){
    int slot = tid + it * 256;                   // 512 slots = 64 c-rows x 8 s-octets
    int r = slot >> 3, sg = slot & 7;
    int sw = sg ^ (r >> 3);
    const float* src = &x[((size_t)(bg * 512 + c0 + r)) * 4096 + s0 + sg * 8];
    f32x4 a = ldf4(src), b = ldf4(src + 4);
    short8 v;
    #pragma unroll
    for (int j = 0; j < 4; ++j){ v[j] = (short)f2bf(a[j]); v[j + 4] = (short)f2bf(b[j]); }
    *reinterpret_cast<short8*>(&t[r * 72 + sw * 8]) = v;
  }
  __syncthreads();
  #pragma unroll
  for (int it = 0; it < 2; ++it){
    int slot = tid + it * 256;                   // 512 slots = 64 s-rows x 8 c-octets
    int j = slot >> 3, i8 = slot & 7;
    short8 v;
    #pragma unroll
    for (int q = 0; q < 8; ++q){
      int c = i8 * 8 + q;
      int sw = (j >> 3) ^ i8;                    // element (c, j): pos = c*72 + ((j>>3)^(c>>3))*8 + (j&7)
      v[q] = (short)t[c * 72 + sw * 8 + (j & 7)];
    }
    *reinterpret_cast<short8*>(&xT[((size_t)(bz * slen) + blockIdx.x * 64 + j) * 512 + c0 + i8 * 8]) = v;
  }
}

// ---------------------------------------------------------------- k1: K -> wsK[bz][l][c] bf16; V -> wsVt[bz][c][l80] bf16
__global__ __launch_bounds__(256) void k1_kvproj(const float* __restrict__ text,
                                                 const float* __restrict__ Wk,
                                                 const float* __restrict__ Wkb,
                                                 const float* __restrict__ Wv,
                                                 const float* __restrict__ Wvb,
                                                 unsigned short* __restrict__ wsK,
                                                 unsigned short* __restrict__ wsVt,
                                                 int b0){
  const int tid = threadIdx.x;
  const int cc = blockIdx.x, lg = blockIdx.y, bz = blockIdx.z;
  const int bg = b0 + bz;
  const int h = tid & 7, cg = tid >> 3;        // 8-way E-split, 32 channel-quads
  const int u0 = cc * 128 + cg * 4;            // concat [K(0..511) ; V(512..1023)]
  const bool isK = (u0 < 512);
  const float* W = isK ? Wk : Wv;
  const int c0 = isK ? u0 : (u0 - 512);
  float acc[4][11];
  #pragma unroll
  for (int c = 0; c < 4; ++c)
    #pragma unroll
    for (int i = 0; i < 11; ++i) acc[c][i] = 0.f;
  const float* tbase = text + ((size_t)(bg * 77 + lg * 11)) * 768 + h * 96;
  for (int e4 = 0; e4 < 24; ++e4){
    f32x4 wv[4];
    #pragma unroll
    for (int c = 0; c < 4; ++c)
      wv[c] = ldf4(&W[(size_t)(c0 + c) * 768 + h * 96 + e4 * 4]);
    #pragma unroll
    for (int i = 0; i < 11; ++i){
      f32x4 tr = ldf4(&tbase[(size_t)i * 768 + e4 * 4]);
      #pragma unroll
      for (int c = 0; c < 4; ++c)
        acc[c][i] += wv[c][0] * tr[0] + wv[c][1] * tr[1] + wv[c][2] * tr[2] + wv[c][3] * tr[3];
    }
  }
  #pragma unroll
  for (int c = 0; c < 4; ++c)
    #pragma unroll
    for (int i = 0; i < 11; ++i){
      float v = acc[c][i];
      v += __shfl_xor(v, 1); v += __shfl_xor(v, 2); v += __shfl_xor(v, 4);
      acc[c][i] = v;
    }
  if (h == 0){
    float bias[4];
    #pragma unroll
    for (int c = 0; c < 4; ++c) bias[c] = isK ? Wkb[c0 + c] : Wvb[c0 + c];
    if (isK){
      #pragma unroll
      for (int i = 0; i < 11; ++i){
        int l = lg * 11 + i;
        short4v pk;
        #pragma unroll
        for (int c = 0; c < 4; ++c) pk[c] = (short)f2bf(acc[c][i] + bias[c]);
        *reinterpret_cast<short4v*>(&wsK[((size_t)(bz * 77 + l)) * 512 + c0]) = pk;
      }
    } else {
      #pragma unroll
      for (int c = 0; c < 4; ++c){
        unsigned short* row = &wsVt[((size_t)(bz * 512 + c0 + c)) * 80];
        #pragma unroll
        for (int i = 0; i < 11; ++i) row[lg * 11 + i] = f2bf(acc[c][i] + bias[c]);
        if (lg == 6){ row[77] = 0; row[78] = 0; row[79] = 0; }
      }
    }
  }
}

// ---------------------------------------------------------------- k2: fused Qproj + attention (transposed)
__global__ __launch_bounds__(256, 2) void k2_attn(const unsigned short* __restrict__ xT,
                                                  const unsigned short* __restrict__ wsK,
                                                  const unsigned short* __restrict__ wsVt,
                                                  const int* __restrict__ amask,
                                                  const unsigned short* __restrict__ wsWq,
                                                  const float* __restrict__ Wqb,
                                                  float* __restrict__ out,
                                                  float* __restrict__ gnacc,
                                                  int b0, int s_base, int slen){
  // R1: phase1 staging A[128][72]+B[128][72] -> Qt[128][136] -> Pt[128][104]
  __shared__ unsigned short R1[18432];
  // R2: Kh[80][136] (phase2) -> Vt[128][104] (phase3)
  __shared__ unsigned short R2[13312];
  __shared__ float maskf[96];

  const int tid = threadIdx.x;
  const int wave = tid >> 6, lane = tid & 63;
  const int m16 = lane & 15, quad = lane >> 4;
  const int st = blockIdx.x, h = blockIdx.y, bz = blockIdx.z;
  const int bg = b0 + bz;
  const int s_glob = s_base + st * 128;
  const int R0 = (wave >> 1) * 64, C0 = (wave & 1) * 64;

  // ---- phase 0: mask bias + Kh -> R2 [80][136] (rows 77..79 zero)
  if (tid < 96){
    int l = tid;
    float mbv = -30000.f;                         // acts as -inf: |scores| <= ~40
    if (l < 77 && amask[bg * 77 + l] != 0) mbv = 0.f;
    maskf[l] = mbv;
  }
  {
    const unsigned short* kb = wsK + (size_t)(bz * 77) * 512 + h * 128;
    #pragma unroll
    for (int it = 0; it < 5; ++it){
      int slot = tid + it * 256;                  // 1280 = 80 rows x 16 octets
      int row = slot >> 4, c8 = slot & 15;
      short8 v = {};
      if (row < 77) v = ld8(&kb[(size_t)row * 512 + c8 * 8]);
      *reinterpret_cast<short8*>(&R2[row * 136 + c8 * 8]) = v;
    }
  }

  // ---- phase 1: Qt = Wq_h[128x512] @ x[512 x 128s], BK=64
  f32x4 acc[4][4];
  #pragma unroll
  for (int mt = 0; mt < 4; ++mt)
    #pragma unroll
    for (int nt = 0; nt < 4; ++nt) acc[mt][nt] = (f32x4){0.f, 0.f, 0.f, 0.f};
  const unsigned short* Aglob = wsWq + (size_t)(h * 128) * 512;
  const unsigned short* Bglob = xT + ((size_t)bz * slen + st * 128) * 512;
  unsigned short* ldsA = R1;
  unsigned short* ldsB = R1 + 9216;
  for (int kc = 0; kc < 8; ++kc){
    #pragma unroll
    for (int it = 0; it < 4; ++it){
      int slot = tid + it * 256; int row = slot >> 3, c8 = slot & 7;
      *reinterpret_cast<short8*>(&ldsA[row * 72 + c8 * 8]) =
          ld8(&Aglob[(size_t)row * 512 + kc * 64 + c8 * 8]);
    }
    #pragma unroll
    for (int it = 0; it < 4; ++it){
      int slot = tid + it * 256; int row = slot >> 3, c8 = slot & 7;
      *reinterpret_cast<short8*>(&ldsB[row * 72 + c8 * 8]) =
          ld8(&Bglob[(size_t)row * 512 + kc * 64 + c8 * 8]);
    }
    __syncthreads();
    #pragma unroll
    for (int kk = 0; kk < 64; kk += 32){
      short8 af[4], bfr[4];
      #pragma unroll
      for (int mt = 0; mt < 4; ++mt)
        af[mt] = *reinterpret_cast<const short8*>(&ldsA[(R0 + mt * 16 + m16) * 72 + kk + quad * 8]);
      #pragma unroll
      for (int nt = 0; nt < 4; ++nt)
        bfr[nt] = *reinterpret_cast<const short8*>(&ldsB[(C0 + nt * 16 + m16) * 72 + kk + quad * 8]);
      #pragma unroll
      for (int mt = 0; mt < 4; ++mt)
        #pragma unroll
        for (int nt = 0; nt < 4; ++nt)
          acc[mt][nt] = __builtin_amdgcn_mfma_f32_16x16x32_bf16(af[mt], bfr[nt], acc[mt][nt], 0, 0, 0);
    }
    __syncthreads();
  }
  // epilogue 1: +bias, Qt -> R1 as [s][d] stride 136 (B-operand layout for phase 2)
  unsigned short* Qt = R1;
  {
    float qb[4][4];
    #pragma unroll
    for (int mt = 0; mt < 4; ++mt)
      #pragma unroll
      for (int r = 0; r < 4; ++r) qb[mt][r] = Wqb[h * 128 + R0 + mt * 16 + quad * 4 + r];
    #pragma unroll
    for (int mt = 0; mt < 4; ++mt)
      #pragma unroll
      for (int nt = 0; nt < 4; ++nt){
        int sl = C0 + nt * 16 + m16;
        short4v pk;
        #pragma unroll
        for (int r = 0; r < 4; ++r) pk[r] = (short)f2bf(acc[mt][nt][r] + qb[mt][r]);
        *reinterpret_cast<short4v*>(&Qt[sl * 136 + R0 + mt * 16 + quad * 4]) = pk;
      }
  }
  __syncthreads();                                  // B1

  // ---- phase 2: St = Kh[80x128] @ Qt[128 x 128s]; waves split N (32 cols each)
  f32x4 acc2[5][2];
  #pragma unroll
  for (int mt = 0; mt < 5; ++mt){ acc2[mt][0] = (f32x4){0.f,0.f,0.f,0.f}; acc2[mt][1] = (f32x4){0.f,0.f,0.f,0.f}; }
  const int cb = wave * 32;
  #pragma unroll
  for (int ks = 0; ks < 4; ++ks){
    short8 bq[2];
    #pragma unroll
    for (int nt = 0; nt < 2; ++nt)
      bq[nt] = *reinterpret_cast<const short8*>(&Qt[(cb + nt * 16 + m16) * 136 + ks * 32 + quad * 8]);
    #pragma unroll
    for (int mt = 0; mt < 5; ++mt){
      short8 ak = *reinterpret_cast<const short8*>(&R2[(mt * 16 + m16) * 136 + ks * 32 + quad * 8]);
      #pragma unroll
      for (int nt = 0; nt < 2; ++nt)
        acc2[mt][nt] = __builtin_amdgcn_mfma_f32_16x16x32_bf16(ak, bq[nt], acc2[mt][nt], 0, 0, 0);
    }
  }
  __syncthreads();                                  // B2: all Qt/Kh reads done

  // ---- softmax over l (lane covers l = mt*16+quad*4+r), Pt -> R1 [s][l] stride 104
  unsigned short* Pt = R1;
  {
    const float scale = 0.08838834764831845f;       // 1/sqrt(128)
    float mb[5][4];
    #pragma unroll
    for (int mt = 0; mt < 5; ++mt)
      #pragma unroll
      for (int r = 0; r < 4; ++r) mb[mt][r] = maskf[mt * 16 + quad * 4 + r];
    #pragma unroll
    for (int nt = 0; nt < 2; ++nt){
      float sv[5][4]; float mx = -3e38f;
      #pragma unroll
      for (int mt = 0; mt < 5; ++mt)
        #pragma unroll
        for (int r = 0; r < 4; ++r){
          float v = acc2[mt][nt][r] * scale + mb[mt][r];
          sv[mt][r] = v; mx = fmaxf(mx, v);
        }
      mx = fmaxf(mx, __shfl_xor(mx, 16)); mx = fmaxf(mx, __shfl_xor(mx, 32));
      float sum = 0.f;
      #pragma unroll
      for (int mt = 0; mt < 5; ++mt)
        #pragma unroll
        for (int r = 0; r < 4; ++r){ float e = __expf(sv[mt][r] - mx); sv[mt][r] = e; sum += e; }
      sum += __shfl_xor(sum, 16); sum += __shfl_xor(sum, 32);
      float inv = 1.0f / sum;
      int sl = cb + nt * 16 + m16;
      #pragma unroll
      for (int mt = 0; mt < 5; ++mt){
        short4v pk;
        #pragma unroll
        for (int r = 0; r < 4; ++r) pk[r] = (short)f2bf(sv[mt][r] * inv);
        *reinterpret_cast<short4v*>(&Pt[sl * 104 + mt * 16 + quad * 4]) = pk;
      }
      short4v z = {};
      *reinterpret_cast<short4v*>(&Pt[sl * 104 + 80 + quad * 4]) = z;  // zero l=80..95
    }
  }
  // ---- Vt -> R2 [128][104] (cols 0..79 from ws, 80..95 zero)
  {
    const unsigned short* vb = wsVt + (size_t)(bz * 512 + h * 128) * 80;
    #pragma unroll
    for (int it = 0; it < 5; ++it){
      int slot = tid + it * 256;                    // rows of 80 contiguous -> linear
      *reinterpret_cast<short8*>(&R2[(slot / 10) * 104 + (slot % 10) * 8]) = ld8(&vb[(size_t)slot * 8]);
    }
    int row = tid >> 1, hf = tid & 1;
    short8 z = {};
    *reinterpret_cast<short8*>(&R2[row * 104 + 80 + hf * 8]) = z;
  }
  __syncthreads();                                  // B3

  // ---- phase 3: Ot = Vt[128x96] @ Pt[96 x 128s]
  f32x4 acc3[4][4];
  #pragma unroll
  for (int mt = 0; mt < 4; ++mt)
    #pragma unroll
    for (int nt = 0; nt < 4; ++nt) acc3[mt][nt] = (f32x4){0.f, 0.f, 0.f, 0.f};
  #pragma unroll
  for (int ks = 0; ks < 3; ++ks){
    short8 av[4], bp[4];
    #pragma unroll
    for (int mt = 0; mt < 4; ++mt)
      av[mt] = *reinterpret_cast<const short8*>(&R2[(R0 + mt * 16 + m16) * 104 + ks * 32 + quad * 8]);
    #pragma unroll
    for (int nt = 0; nt < 4; ++nt)
      bp[nt] = *reinterpret_cast<const short8*>(&Pt[(C0 + nt * 16 + m16) * 104 + ks * 32 + quad * 8]);
    #pragma unroll
    for (int mt = 0; mt < 4; ++mt)
      #pragma unroll
      for (int nt = 0; nt < 4; ++nt)
        acc3[mt][nt] = __builtin_amdgcn_mfma_f32_16x16x32_bf16(av[mt], bp[nt], acc3[mt][nt], 0, 0, 0);
  }
  // ---- epilogue: fp32 store + GroupNorm partials (each wave's 64x64 tile is one group)
  float sum = 0.f, ssq = 0.f;
  #pragma unroll
  for (int mt = 0; mt < 4; ++mt)
    #pragma unroll
    for (int nt = 0; nt < 4; ++nt){
      int sidx = s_glob + C0 + nt * 16 + m16;
      #pragma unroll
      for (int r = 0; r < 4; ++r){
        float v = acc3[mt][nt][r];
        sum += v; ssq += v * v;
        int d = h * 128 + R0 + mt * 16 + quad * 4 + r;
        out[(size_t)(bg * 512 + d) * 4096 + sidx] = v;
      }
    }
  #pragma unroll
  for (int off = 1; off < 64; off <<= 1){ sum += __shfl_xor(sum, off); ssq += __shfl_xor(ssq, off); }
  if (lane == 0){
    int g = h * 2 + (R0 >> 6);
    atomicAdd(&gnacc[(bg * 8 + g) * 2],     sum);
    atomicAdd(&gnacc[(bg * 8 + g) * 2 + 1], ssq);
  }
}

// ---------------------------------------------------------------- k3: GroupNorm apply, in-place on fp32 d_out
__global__ __launch_bounds__(256) void k3_gn(float* __restrict__ out,
                                             const float* __restrict__ gnacc,
                                             const float* __restrict__ gns,
                                             const float* __restrict__ gnb){
  const int bx = blockIdx.x;                 // bx = b*512 + c
  const int b = bx >> 9, c = bx & 511;
  const int g = c >> 6;
  const float s  = gnacc[(b * 8 + g) * 2];
  const float ss = gnacc[(b * 8 + g) * 2 + 1];
  const float invN = 1.f / 262144.f;         // 64 ch * 4096 spatial per group
  const float mean = s * invN;
  const float var  = ss * invN - mean * mean;
  const float rstd = rsqrtf(fmaxf(var, 0.f) + 1e-5f);
  const float a  = rstd * gns[c];
  const float bb = gnb[c] - mean * a;
  const size_t base = (size_t)bx * 4096;
  #pragma unroll
  for (int p = 0; p < 4; ++p){
    size_t off = base + p * 1024 + threadIdx.x * 4;
    f32x4 v = ldf4(&out[off]);
    f32x4 o;
    #pragma unroll
    for (int j = 0; j < 4; ++j) o[j] = v[j] * a + bb;
    *reinterpret_cast<f32x4*>(&out[off]) = o;
  }
}

// ---------------------------------------------------------------- launch
extern "C" void kernel_launch(void* const* d_in, const int* in_sizes, int n_in,
                              void* d_out, int out_size, void* d_ws, size_t ws_size,
                              hipStream_t stream){
  (void)in_sizes; (void)n_in; (void)out_size;
  const float* x    = (const float*)d_in[0];
  const float* text = (const float*)d_in[1];
  const int*   am   = (const int*)d_in[2];
  const float* Wq   = (const float*)d_in[3];
  const float* Wqb  = (const float*)d_in[4];
  const float* Wk   = (const float*)d_in[5];
  const float* Wkb  = (const float*)d_in[6];
  const float* Wv   = (const float*)d_in[7];
  const float* Wvb  = (const float*)d_in[8];
  const float* gns  = (const float*)d_in[9];
  const float* gnb  = (const float*)d_in[10];
  float* out = (float*)d_out;

  // ---- pick the largest batch/s slice that fits ws_size ----
  // ws: gnacc 512 B + wsWq 512*512*2 + SB*77*512*2 (K) + SB*512*80*2 (Vt) + SB*SLEN*512*2 (xT)
  auto need = [](int SB, int SLEN) -> size_t {
    return 512ull + 524288ull + (size_t)SB * 78848ull + (size_t)SB * 81920ull
         + (size_t)SB * SLEN * 1024ull;
  };
  int SB = 8, SLEN = 4096;
  if      (ws_size >= need(8, 4096)) { SB = 8; SLEN = 4096; }
  else if (ws_size >= need(4, 4096)) { SB = 4; SLEN = 4096; }
  else if (ws_size >= need(2, 4096)) { SB = 2; SLEN = 4096; }
  else if (ws_size >= need(1, 4096)) { SB = 1; SLEN = 4096; }
  else if (ws_size >= need(1, 1024)) { SB = 1; SLEN = 1024; }
  else                               { SB = 1; SLEN = 256;  } // last resort

  uint8_t* ws = (uint8_t*)d_ws;
  float*          gnacc = (float*)ws;                                   // 128 floats, full batch
  unsigned short* wsWq  = (unsigned short*)(ws + 512);                  // [512][512] bf16
  unsigned short* wsK   = wsWq + 512 * 512;                             // [SB][77][512]
  unsigned short* wsVt  = wsK  + (size_t)SB * 77 * 512;                 // [SB][512][80]
  unsigned short* xT    = wsVt + (size_t)SB * 512 * 80;                 // [SB][SLEN][512]

  hipMemsetAsync(gnacc, 0, 128 * sizeof(float), stream);
  k_prep<<<256, 256, 0, stream>>>(Wq, wsWq);
  for (int b0 = 0; b0 < 8; b0 += SB){
    k1_kvproj<<<dim3(8, 7, SB), 256, 0, stream>>>(text, Wk, Wkb, Wv, Wvb, wsK, wsVt, b0);
    for (int s_base = 0; s_base < 4096; s_base += SLEN){
      k0_transpose<<<dim3(SLEN / 64, 8, SB), 256, 0, stream>>>(x, xT, b0, s_base, SLEN);
      k2_attn<<<dim3(SLEN / 128, 4, SB), 256, 0, stream>>>(xT, wsK, wsVt, am, wsWq, Wqb,
                                                           out, gnacc, b0, s_base, SLEN);
    }
  }
  k3_gn<<<4096, 256, 0, stream>>>(out, gnacc, gns, gnb);
}

// Round 4
// 254.760 us; speedup vs baseline: 1.2599x; 1.2599x over previous
//
#include <hip/hip_runtime.h>
#include <hip/hip_bf16.h>
#include <cstdint>

// CrossAttentionMultiHead: B=8, C=512, H=W=64 (S=4096), L=77, E=768, heads=4 (dh=128), GN groups=8.
// FP32 I/O; attention_mask int32. Compute in bf16 MFMA, fp32 accum.
// Pipeline: k_prep Wq->bf16 | per slice: k1 K/V proj (MFMA) | k0 x->xT (fp32->bf16 transpose) |
// k2 fused Qproj+attention (MFMA) + GN partials | k3 GroupNorm apply in-place on fp32 d_out.

typedef __attribute__((ext_vector_type(8))) short short8;
typedef __attribute__((ext_vector_type(4))) short short4v;
typedef __attribute__((ext_vector_type(4))) float f32x4;

#define DEV __device__ __forceinline__

DEV float bf2f(unsigned short u){ union{uint32_t i; float f;} x; x.i = ((uint32_t)u) << 16; return x.f; }
DEV unsigned short f2bf(float f){ __hip_bfloat16 h = __float2bfloat16(f); return *reinterpret_cast<unsigned short*>(&h); }
DEV short8 ld8(const unsigned short* p){ return *reinterpret_cast<const short8*>(p); }
DEV f32x4 ldf4(const float* p){ return *reinterpret_cast<const f32x4*>(p); }

// ---------------------------------------------------------------- k_prep: Wq fp32 -> bf16
__global__ __launch_bounds__(256) void k_prep(const float* __restrict__ Wq,
                                              unsigned short* __restrict__ wsWq){
  int i = (blockIdx.x * 256 + threadIdx.x) * 4;
  f32x4 v = ldf4(&Wq[i]);
  short4v o;
  #pragma unroll
  for (int j = 0; j < 4; ++j) o[j] = (short)f2bf(v[j]);
  *reinterpret_cast<short4v*>(&wsWq[i]) = o;
}

// ---------------------------------------------------------------- k0: x[b][c][s] fp32 -> xT[bz][s-s_base][c] bf16
__global__ __launch_bounds__(256) void k0_transpose(const float* __restrict__ x,
                                                    unsigned short* __restrict__ xT,
                                                    int b0, int s_base, int slen){
  __shared__ unsigned short t[64 * 72];          // 64x64 tile, stride 72, XOR-swizzled s-octets
  const int tid = threadIdx.x;
  const int s0 = s_base + blockIdx.x * 64, c0 = blockIdx.y * 64, bz = blockIdx.z;
  const int bg = b0 + bz;
  #pragma unroll
  for (int it = 0; it < 2; ++it){
    int slot = tid + it * 256;                   // 512 slots = 64 c-rows x 8 s-octets
    int r = slot >> 3, sg = slot & 7;
    int sw = sg ^ (r >> 3);
    const float* src = &x[((size_t)(bg * 512 + c0 + r)) * 4096 + s0 + sg * 8];
    f32x4 a = ldf4(src), b = ldf4(src + 4);
    short8 v;
    #pragma unroll
    for (int j = 0; j < 4; ++j){ v[j] = (short)f2bf(a[j]); v[j + 4] = (short)f2bf(b[j]); }
    *reinterpret_cast<short8*>(&t[r * 72 + sw * 8]) = v;
  }
  __syncthreads();
  #pragma unroll
  for (int it = 0; it < 2; ++it){
    int slot = tid + it * 256;                   // 512 slots = 64 s-rows x 8 c-octets
    int j = slot >> 3, i8 = slot & 7;
    short8 v;
    #pragma unroll
    for (int q = 0; q < 8; ++q){
      int c = i8 * 8 + q;
      int sw = (j >> 3) ^ i8;                    // element (c, j): pos = c*72 + ((j>>3)^(c>>3))*8 + (j&7)
      v[q] = (short)t[c * 72 + sw * 8 + (j & 7)];
    }
    *reinterpret_cast<short8*>(&xT[((size_t)(bz * slen) + blockIdx.x * 64 + j) * 512 + c0 + i8 * 8]) = v;
  }
}

// ---------------------------------------------------------------- k1 (MFMA): K -> wsK[bz][l][c]; V -> wsVt[bz][c][l80]
// Per block (uc, bz): out[80l x 128u] = text[80 x 768] @ W'[u0..u0+128][768]^T, BK=64.
// u-chunks 0..3 -> Wk rows, 4..7 -> Wv rows (128 | 512 so each block is pure K or pure V).
__global__ __launch_bounds__(256) void k1_kvproj(const float* __restrict__ text,
                                                 const float* __restrict__ Wk,
                                                 const float* __restrict__ Wkb,
                                                 const float* __restrict__ Wv,
                                                 const float* __restrict__ Wvb,
                                                 unsigned short* __restrict__ wsK,
                                                 unsigned short* __restrict__ wsVt,
                                                 int b0){
  __shared__ unsigned short At[80 * 72];         // text tile [l][e64]
  __shared__ unsigned short Bt[128 * 72];        // W    tile [u][e64]
  const int tid = threadIdx.x;
  const int wave = tid >> 6, lane = tid & 63;
  const int m16 = lane & 15, quad = lane >> 4;
  const int uc = blockIdx.x, bz = blockIdx.y, bg = b0 + bz;
  const int u0 = uc * 128;
  const bool isK = (u0 < 512);
  const float* W  = isK ? Wk  : Wv;
  const float* Wb = isK ? Wkb : Wvb;
  const int c0 = u0 & 511;
  const int nb = wave * 32;                      // 4 waves split N=128 into 32 each

  f32x4 acc[5][2];
  #pragma unroll
  for (int mt = 0; mt < 5; ++mt){ acc[mt][0] = (f32x4){0.f,0.f,0.f,0.f}; acc[mt][1] = (f32x4){0.f,0.f,0.f,0.f}; }

  for (int kc = 0; kc < 12; ++kc){
    const int e0 = kc * 64;
    #pragma unroll
    for (int it = 0; it < 5; ++it){
      int slot = tid + it * 256;                 // 1280 = 80 rows x 16 f32x4
      int row = slot >> 4, e4 = (slot & 15) * 4;
      f32x4 v = (row < 77) ? ldf4(&text[((size_t)(bg * 77 + row)) * 768 + e0 + e4])
                           : (f32x4){0.f, 0.f, 0.f, 0.f};
      short4v o;
      #pragma unroll
      for (int j = 0; j < 4; ++j) o[j] = (short)f2bf(v[j]);
      *reinterpret_cast<short4v*>(&At[row * 72 + e4]) = o;
    }
    #pragma unroll
    for (int it = 0; it < 8; ++it){
      int slot = tid + it * 256;                 // 2048 = 128 rows x 16 f32x4
      int row = slot >> 4, e4 = (slot & 15) * 4;
      f32x4 v = ldf4(&W[((size_t)(c0 + row)) * 768 + e0 + e4]);
      short4v o;
      #pragma unroll
      for (int j = 0; j < 4; ++j) o[j] = (short)f2bf(v[j]);
      *reinterpret_cast<short4v*>(&Bt[row * 72 + e4]) = o;
    }
    __syncthreads();
    #pragma unroll
    for (int kk = 0; kk < 64; kk += 32){
      short8 bfr[2], af[5];
      #pragma unroll
      for (int nt = 0; nt < 2; ++nt)
        bfr[nt] = *reinterpret_cast<const short8*>(&Bt[(nb + nt * 16 + m16) * 72 + kk + quad * 8]);
      #pragma unroll
      for (int mt = 0; mt < 5; ++mt)
        af[mt] = *reinterpret_cast<const short8*>(&At[(mt * 16 + m16) * 72 + kk + quad * 8]);
      #pragma unroll
      for (int mt = 0; mt < 5; ++mt)
        #pragma unroll
        for (int nt = 0; nt < 2; ++nt)
          acc[mt][nt] = __builtin_amdgcn_mfma_f32_16x16x32_bf16(af[mt], bfr[nt], acc[mt][nt], 0, 0, 0);
    }
    __syncthreads();
  }
  // epilogue: +bias; K -> [l][c] scalar stores, V -> [c][l] short4 stores.
  float bias[2];
  #pragma unroll
  for (int nt = 0; nt < 2; ++nt) bias[nt] = Wb[c0 + nb + nt * 16 + m16];
  if (isK){
    #pragma unroll
    for (int mt = 0; mt < 5; ++mt)
      #pragma unroll
      for (int nt = 0; nt < 2; ++nt){
        int c = c0 + nb + nt * 16 + m16;
        #pragma unroll
        for (int r = 0; r < 4; ++r){
          int l = mt * 16 + quad * 4 + r;
          if (l < 77) wsK[((size_t)(bz * 77 + l)) * 512 + c] = f2bf(acc[mt][nt][r] + bias[nt]);
        }
      }
  } else {
    #pragma unroll
    for (int mt = 0; mt < 5; ++mt)
      #pragma unroll
      for (int nt = 0; nt < 2; ++nt){
        int c = c0 + nb + nt * 16 + m16;
        int l0 = mt * 16 + quad * 4;
        short4v pk;
        #pragma unroll
        for (int r = 0; r < 4; ++r) pk[r] = (short)f2bf(acc[mt][nt][r] + bias[nt]);
        // pad cols 77..79 hold bias, harmless: k2's P rows >=77 are exactly 0.
        *reinterpret_cast<short4v*>(&wsVt[((size_t)(bz * 512 + c)) * 80 + l0]) = pk;
      }
  }
}

// ---------------------------------------------------------------- k2: fused Qproj + attention (transposed)
__global__ __launch_bounds__(256, 2) void k2_attn(const unsigned short* __restrict__ xT,
                                                  const unsigned short* __restrict__ wsK,
                                                  const unsigned short* __restrict__ wsVt,
                                                  const int* __restrict__ amask,
                                                  const unsigned short* __restrict__ wsWq,
                                                  const float* __restrict__ Wqb,
                                                  float* __restrict__ out,
                                                  float* __restrict__ gnacc,
                                                  int b0, int s_base, int slen){
  // R1: phase1 staging A[128][72]+B[128][72] -> Qt[128][136] -> Pt[128][104]
  __shared__ unsigned short R1[18432];
  // R2: Kh[80][136] (phase2) -> Vt[128][104] (phase3)
  __shared__ unsigned short R2[13312];
  __shared__ float maskf[96];

  const int tid = threadIdx.x;
  const int wave = tid >> 6, lane = tid & 63;
  const int m16 = lane & 15, quad = lane >> 4;
  const int st = blockIdx.x, h = blockIdx.y, bz = blockIdx.z;
  const int bg = b0 + bz;
  const int s_glob = s_base + st * 128;
  const int R0 = (wave >> 1) * 64, C0 = (wave & 1) * 64;

  // ---- phase 0: mask bias + Kh -> R2 [80][136] (rows 77..79 zero)
  if (tid < 96){
    int l = tid;
    float mbv = -30000.f;                         // acts as -inf: |scores| <= ~40
    if (l < 77 && amask[bg * 77 + l] != 0) mbv = 0.f;
    maskf[l] = mbv;
  }
  {
    const unsigned short* kb = wsK + (size_t)(bz * 77) * 512 + h * 128;
    #pragma unroll
    for (int it = 0; it < 5; ++it){
      int slot = tid + it * 256;                  // 1280 = 80 rows x 16 octets
      int row = slot >> 4, c8 = slot & 15;
      short8 v = {};
      if (row < 77) v = ld8(&kb[(size_t)row * 512 + c8 * 8]);
      *reinterpret_cast<short8*>(&R2[row * 136 + c8 * 8]) = v;
    }
  }

  // ---- phase 1: Qt = Wq_h[128x512] @ x[512 x 128s], BK=64
  f32x4 acc[4][4];
  #pragma unroll
  for (int mt = 0; mt < 4; ++mt)
    #pragma unroll
    for (int nt = 0; nt < 4; ++nt) acc[mt][nt] = (f32x4){0.f, 0.f, 0.f, 0.f};
  const unsigned short* Aglob = wsWq + (size_t)(h * 128) * 512;
  const unsigned short* Bglob = xT + ((size_t)bz * slen + st * 128) * 512;
  unsigned short* ldsA = R1;
  unsigned short* ldsB = R1 + 9216;
  for (int kc = 0; kc < 8; ++kc){
    #pragma unroll
    for (int it = 0; it < 4; ++it){
      int slot = tid + it * 256; int row = slot >> 3, c8 = slot & 7;
      *reinterpret_cast<short8*>(&ldsA[row * 72 + c8 * 8]) =
          ld8(&Aglob[(size_t)row * 512 + kc * 64 + c8 * 8]);
    }
    #pragma unroll
    for (int it = 0; it < 4; ++it){
      int slot = tid + it * 256; int row = slot >> 3, c8 = slot & 7;
      *reinterpret_cast<short8*>(&ldsB[row * 72 + c8 * 8]) =
          ld8(&Bglob[(size_t)row * 512 + kc * 64 + c8 * 8]);
    }
    __syncthreads();
    #pragma unroll
    for (int kk = 0; kk < 64; kk += 32){
      short8 af[4], bfr[4];
      #pragma unroll
      for (int mt = 0; mt < 4; ++mt)
        af[mt] = *reinterpret_cast<const short8*>(&ldsA[(R0 + mt * 16 + m16) * 72 + kk + quad * 8]);
      #pragma unroll
      for (int nt = 0; nt < 4; ++nt)
        bfr[nt] = *reinterpret_cast<const short8*>(&ldsB[(C0 + nt * 16 + m16) * 72 + kk + quad * 8]);
      #pragma unroll
      for (int mt = 0; mt < 4; ++mt)
        #pragma unroll
        for (int nt = 0; nt < 4; ++nt)
          acc[mt][nt] = __builtin_amdgcn_mfma_f32_16x16x32_bf16(af[mt], bfr[nt], acc[mt][nt], 0, 0, 0);
    }
    __syncthreads();
  }
  // epilogue 1: +bias, Qt -> R1 as [s][d] stride 136 (B-operand layout for phase 2)
  unsigned short* Qt = R1;
  {
    float qb[4][4];
    #pragma unroll
    for (int mt = 0; mt < 4; ++mt)
      #pragma unroll
      for (int r = 0; r < 4; ++r) qb[mt][r] = Wqb[h * 128 + R0 + mt * 16 + quad * 4 + r];
    #pragma unroll
    for (int mt = 0; mt < 4; ++mt)
      #pragma unroll
      for (int nt = 0; nt < 4; ++nt){
        int sl = C0 + nt * 16 + m16;
        short4v pk;
        #pragma unroll
        for (int r = 0; r < 4; ++r) pk[r] = (short)f2bf(acc[mt][nt][r] + qb[mt][r]);
        *reinterpret_cast<short4v*>(&Qt[sl * 136 + R0 + mt * 16 + quad * 4]) = pk;
      }
  }
  __syncthreads();                                  // B1

  // ---- phase 2: St = Kh[80x128] @ Qt[128 x 128s]; waves split N (32 cols each)
  f32x4 acc2[5][2];
  #pragma unroll
  for (int mt = 0; mt < 5; ++mt){ acc2[mt][0] = (f32x4){0.f,0.f,0.f,0.f}; acc2[mt][1] = (f32x4){0.f,0.f,0.f,0.f}; }
  const int cb = wave * 32;
  #pragma unroll
  for (int ks = 0; ks < 4; ++ks){
    short8 bq[2];
    #pragma unroll
    for (int nt = 0; nt < 2; ++nt)
      bq[nt] = *reinterpret_cast<const short8*>(&Qt[(cb + nt * 16 + m16) * 136 + ks * 32 + quad * 8]);
    #pragma unroll
    for (int mt = 0; mt < 5; ++mt){
      short8 ak = *reinterpret_cast<const short8*>(&R2[(mt * 16 + m16) * 136 + ks * 32 + quad * 8]);
      #pragma unroll
      for (int nt = 0; nt < 2; ++nt)
        acc2[mt][nt] = __builtin_amdgcn_mfma_f32_16x16x32_bf16(ak, bq[nt], acc2[mt][nt], 0, 0, 0);
    }
  }
  __syncthreads();                                  // B2: all Qt/Kh reads done

  // ---- softmax over l (lane covers l = mt*16+quad*4+r), Pt -> R1 [s][l] stride 104
  unsigned short* Pt = R1;
  {
    const float scale = 0.08838834764831845f;       // 1/sqrt(128)
    float mb[5][4];
    #pragma unroll
    for (int mt = 0; mt < 5; ++mt)
      #pragma unroll
      for (int r = 0; r < 4; ++r) mb[mt][r] = maskf[mt * 16 + quad * 4 + r];
    #pragma unroll
    for (int nt = 0; nt < 2; ++nt){
      float sv[5][4]; float mx = -3e38f;
      #pragma unroll
      for (int mt = 0; mt < 5; ++mt)
        #pragma unroll
        for (int r = 0; r < 4; ++r){
          float v = acc2[mt][nt][r] * scale + mb[mt][r];
          sv[mt][r] = v; mx = fmaxf(mx, v);
        }
      mx = fmaxf(mx, __shfl_xor(mx, 16)); mx = fmaxf(mx, __shfl_xor(mx, 32));
      float sum = 0.f;
      #pragma unroll
      for (int mt = 0; mt < 5; ++mt)
        #pragma unroll
        for (int r = 0; r < 4; ++r){ float e = __expf(sv[mt][r] - mx); sv[mt][r] = e; sum += e; }
      sum += __shfl_xor(sum, 16); sum += __shfl_xor(sum, 32);
      float inv = 1.0f / sum;
      int sl = cb + nt * 16 + m16;
      #pragma unroll
      for (int mt = 0; mt < 5; ++mt){
        short4v pk;
        #pragma unroll
        for (int r = 0; r < 4; ++r) pk[r] = (short)f2bf(sv[mt][r] * inv);
        *reinterpret_cast<short4v*>(&Pt[sl * 104 + mt * 16 + quad * 4]) = pk;
      }
      short4v z = {};
      *reinterpret_cast<short4v*>(&Pt[sl * 104 + 80 + quad * 4]) = z;  // zero l=80..95
    }
  }
  // ---- Vt -> R2 [128][104] (cols 0..79 from ws, 80..95 zero)
  {
    const unsigned short* vb = wsVt + (size_t)(bz * 512 + h * 128) * 80;
    #pragma unroll
    for (int it = 0; it < 5; ++it){
      int slot = tid + it * 256;                    // rows of 80 contiguous -> linear
      *reinterpret_cast<short8*>(&R2[(slot / 10) * 104 + (slot % 10) * 8]) = ld8(&vb[(size_t)slot * 8]);
    }
    int row = tid >> 1, hf = tid & 1;
    short8 z = {};
    *reinterpret_cast<short8*>(&R2[row * 104 + 80 + hf * 8]) = z;
  }
  __syncthreads();                                  // B3

  // ---- phase 3: Ot = Vt[128x96] @ Pt[96 x 128s]
  f32x4 acc3[4][4];
  #pragma unroll
  for (int mt = 0; mt < 4; ++mt)
    #pragma unroll
    for (int nt = 0; nt < 4; ++nt) acc3[mt][nt] = (f32x4){0.f, 0.f, 0.f, 0.f};
  #pragma unroll
  for (int ks = 0; ks < 3; ++ks){
    short8 av[4], bp[4];
    #pragma unroll
    for (int mt = 0; mt < 4; ++mt)
      av[mt] = *reinterpret_cast<const short8*>(&R2[(R0 + mt * 16 + m16) * 104 + ks * 32 + quad * 8]);
    #pragma unroll
    for (int nt = 0; nt < 4; ++nt)
      bp[nt] = *reinterpret_cast<const short8*>(&Pt[(C0 + nt * 16 + m16) * 104 + ks * 32 + quad * 8]);
    #pragma unroll
    for (int mt = 0; mt < 4; ++mt)
      #pragma unroll
      for (int nt = 0; nt < 4; ++nt)
        acc3[mt][nt] = __builtin_amdgcn_mfma_f32_16x16x32_bf16(av[mt], bp[nt], acc3[mt][nt], 0, 0, 0);
  }
  // ---- epilogue: fp32 store + GroupNorm partials (each wave's 64x64 tile is one group)
  float sum = 0.f, ssq = 0.f;
  #pragma unroll
  for (int mt = 0; mt < 4; ++mt)
    #pragma unroll
    for (int nt = 0; nt < 4; ++nt){
      int sidx = s_glob + C0 + nt * 16 + m16;
      #pragma unroll
      for (int r = 0; r < 4; ++r){
        float v = acc3[mt][nt][r];
        sum += v; ssq += v * v;
        int d = h * 128 + R0 + mt * 16 + quad * 4 + r;
        out[(size_t)(bg * 512 + d) * 4096 + sidx] = v;
      }
    }
  #pragma unroll
  for (int off = 1; off < 64; off <<= 1){ sum += __shfl_xor(sum, off); ssq += __shfl_xor(ssq, off); }
  if (lane == 0){
    int g = h * 2 + (R0 >> 6);
    atomicAdd(&gnacc[(bg * 8 + g) * 2],     sum);
    atomicAdd(&gnacc[(bg * 8 + g) * 2 + 1], ssq);
  }
}

// ---------------------------------------------------------------- k3: GroupNorm apply, in-place on fp32 d_out
__global__ __launch_bounds__(256) void k3_gn(float* __restrict__ out,
                                             const float* __restrict__ gnacc,
                                             const float* __restrict__ gns,
                                             const float* __restrict__ gnb){
  const int bx = blockIdx.x;                 // bx = b*512 + c
  const int b = bx >> 9, c = bx & 511;
  const int g = c >> 6;
  const float s  = gnacc[(b * 8 + g) * 2];
  const float ss = gnacc[(b * 8 + g) * 2 + 1];
  const float invN = 1.f / 262144.f;         // 64 ch * 4096 spatial per group
  const float mean = s * invN;
  const float var  = ss * invN - mean * mean;
  const float rstd = rsqrtf(fmaxf(var, 0.f) + 1e-5f);
  const float a  = rstd * gns[c];
  const float bb = gnb[c] - mean * a;
  const size_t base = (size_t)bx * 4096;
  #pragma unroll
  for (int p = 0; p < 4; ++p){
    size_t off = base + p * 1024 + threadIdx.x * 4;
    f32x4 v = ldf4(&out[off]);
    f32x4 o;
    #pragma unroll
    for (int j = 0; j < 4; ++j) o[j] = v[j] * a + bb;
    *reinterpret_cast<f32x4*>(&out[off]) = o;
  }
}

// ---------------------------------------------------------------- launch
extern "C" void kernel_launch(void* const* d_in, const int* in_sizes, int n_in,
                              void* d_out, int out_size, void* d_ws, size_t ws_size,
                              hipStream_t stream){
  (void)in_sizes; (void)n_in; (void)out_size;
  const float* x    = (const float*)d_in[0];
  const float* text = (const float*)d_in[1];
  const int*   am   = (const int*)d_in[2];
  const float* Wq   = (const float*)d_in[3];
  const float* Wqb  = (const float*)d_in[4];
  const float* Wk   = (const float*)d_in[5];
  const float* Wkb  = (const float*)d_in[6];
  const float* Wv   = (const float*)d_in[7];
  const float* Wvb  = (const float*)d_in[8];
  const float* gns  = (const float*)d_in[9];
  const float* gnb  = (const float*)d_in[10];
  float* out = (float*)d_out;

  // ---- pick the largest batch/s slice that fits ws_size ----
  // ws: gnacc 512 B + wsWq 512*512*2 + SB*77*512*2 (K) + SB*512*80*2 (Vt) + SB*SLEN*512*2 (xT)
  auto need = [](int SB, int SLEN) -> size_t {
    return 512ull + 524288ull + (size_t)SB * 78848ull + (size_t)SB * 81920ull
         + (size_t)SB * SLEN * 1024ull;
  };
  int SB = 8, SLEN = 4096;
  if      (ws_size >= need(8, 4096)) { SB = 8; SLEN = 4096; }
  else if (ws_size >= need(4, 4096)) { SB = 4; SLEN = 4096; }
  else if (ws_size >= need(2, 4096)) { SB = 2; SLEN = 4096; }
  else if (ws_size >= need(1, 4096)) { SB = 1; SLEN = 4096; }
  else if (ws_size >= need(1, 1024)) { SB = 1; SLEN = 1024; }
  else                               { SB = 1; SLEN = 256;  } // last resort

  uint8_t* ws = (uint8_t*)d_ws;
  float*          gnacc = (float*)ws;                                   // 128 floats, full batch
  unsigned short* wsWq  = (unsigned short*)(ws + 512);                  // [512][512] bf16
  unsigned short* wsK   = wsWq + 512 * 512;                             // [SB][77][512]
  unsigned short* wsVt  = wsK  + (size_t)SB * 77 * 512;                 // [SB][512][80]
  unsigned short* xT    = wsVt + (size_t)SB * 512 * 80;                 // [SB][SLEN][512]

  hipMemsetAsync(gnacc, 0, 128 * sizeof(float), stream);
  k_prep<<<256, 256, 0, stream>>>(Wq, wsWq);
  for (int b0 = 0; b0 < 8; b0 += SB){
    k1_kvproj<<<dim3(8, SB), 256, 0, stream>>>(text, Wk, Wkb, Wv, Wvb, wsK, wsVt, b0);
    for (int s_base = 0; s_base < 4096; s_base += SLEN){
      k0_transpose<<<dim3(SLEN / 64, 8, SB), 256, 0, stream>>>(x, xT, b0, s_base, SLEN);
      k2_attn<<<dim3(SLEN / 128, 4, SB), 256, 0, stream>>>(xT, wsK, wsVt, am, wsWq, Wqb,
                                                           out, gnacc, b0, s_base, SLEN);
    }
  }
  k3_gn<<<4096, 256, 0, stream>>>(out, gnacc, gns, gnb);
}